// Round 4
// baseline (329.776 us; speedup 1.0000x reference)
//
#include <hip/hip_runtime.h>
#include <stdint.h>

// out[8192,4096] = x[8192,4096] @ (A[4096,16] @ B[16,4096]), ALL FP32.
// v5: v4 skeleton (spill-free, WRITE_SIZE==O confirmed) + bytes-in-flight fix.
//   v4 was HBM-latency-bound: scalar X loads = 64 B/wave-instr, ~5.6 KB/CU
//   outstanding -> measured 1.43 TB/s (need ~15 KB/CU for 6.3 TB/s).
// Phase A (kq,rq): lane=4*kq+rq. Per t: x = float4 X[row][t*64+kq*4]
//   (256 B/row/instr, 4-way rq broadcast), A[(k0+j)][4rq..4rq+3] float4
//   (1 KB/instr coalesced). acc = 2 float4. Manual 2-stage pipeline:
//   A-loads issued BEFORE next-x loads so vmcnt waits on A leave the X
//   stream in flight (~1 KB/wave -> ~16 KB/CU outstanding).
//   Reduce over kq: shfl_xor 4,8,16,32; lanes 0..3 write t_s.
// Phase B: wave owns a ROW PAIR; each B-value read from LDS feeds 2 rows
//   (LDS read bytes/output 64->32 B). B staged per 32 KB chunk as in v4.
// Live set <= ~50 floats at every point (64-VGPR proof from v4 carries).

#define KD 4096
#define ND 4096
#define NR 16
#define BLK 256
#define MB 8          // rows per block = 4 waves * 2
#define NCHUNK 512    // Phase-B column chunk (32 KB LDS)

#define FMA4(ACC, XS, A4)                          \
    ACC.x = fmaf((XS), (A4).x, ACC.x);             \
    ACC.y = fmaf((XS), (A4).y, ACC.y);             \
    ACC.z = fmaf((XS), (A4).z, ACC.z);             \
    ACC.w = fmaf((XS), (A4).w, ACC.w);

#define RED1(C, OFF) C += __shfl_xor(C, OFF, 64);
#define RED(OFF)                                   \
    RED1(acc0.x, OFF) RED1(acc0.y, OFF)            \
    RED1(acc0.z, OFF) RED1(acc0.w, OFF)            \
    RED1(acc1.x, OFF) RED1(acc1.y, OFF)            \
    RED1(acc1.z, OFF) RED1(acc1.w, OFF)

// one LDS B-row read feeds both rows of the pair
#define FMAB2(TA, TB, R)                                                       \
    {                                                                          \
        const float4 b_ = *reinterpret_cast<const float4*>(bp + (R) * NCHUNK); \
        oa.x = fmaf((TA), b_.x, oa.x);  ob.x = fmaf((TB), b_.x, ob.x);         \
        oa.y = fmaf((TA), b_.y, oa.y);  ob.y = fmaf((TB), b_.y, ob.y);         \
        oa.z = fmaf((TA), b_.z, oa.z);  ob.z = fmaf((TB), b_.z, ob.z);         \
        oa.w = fmaf((TA), b_.w, oa.w);  ob.w = fmaf((TB), b_.w, ob.w);         \
    }

__global__ __launch_bounds__(BLK)
void lora_fused(const float* __restrict__ X,
                const float* __restrict__ A,
                const float* __restrict__ Bm,
                float* __restrict__ O)
{
    __shared__ float t_s[MB][NR];
    __shared__ float bs[NR * NCHUNK];   // 32 KB

    const int tid  = threadIdx.x;
    const int wv   = tid >> 6;
    const int lane = tid & 63;
    const int rq   = lane & 3;     // rank quad: ranks 4rq..4rq+3
    const int kq   = lane >> 2;    // k quad group 0..15
    const size_t m0 = (size_t)blockIdx.x * MB;

    // ---------------- Phase A: T = X @ A ----------------
    // k = t*64 + kq*4 + j,  j = 0..3 (components of the x float4)
    const float* xp0 = X + (m0 + 2 * wv) * (size_t)KD + kq * 4;
    const float* xp1 = xp0 + KD;
    const float* ap  = A + (size_t)kq * 4 * NR + rq * 4;

    float4 acc0 = {0.f, 0.f, 0.f, 0.f};
    float4 acc1 = {0.f, 0.f, 0.f, 0.f};

    float4 nx0 = *reinterpret_cast<const float4*>(xp0);
    float4 nx1 = *reinterpret_cast<const float4*>(xp1);

    #pragma unroll 1
    for (int t = 0; t < KD / 64; ++t) {
        const float4 x0 = nx0;
        const float4 x1 = nx1;

        // A-loads first: the vmcnt wait before the FMAs only drains these,
        // leaving the next-x stream loads in flight.
        const float* at = ap + (size_t)t * (64 * NR);
        const float4 a0 = *reinterpret_cast<const float4*>(at);
        const float4 a1 = *reinterpret_cast<const float4*>(at + NR);
        const float4 a2 = *reinterpret_cast<const float4*>(at + 2 * NR);
        const float4 a3 = *reinterpret_cast<const float4*>(at + 3 * NR);

        if (t < KD / 64 - 1) {   // wave-uniform branch
            nx0 = *reinterpret_cast<const float4*>(xp0 + (size_t)(t + 1) * 64);
            nx1 = *reinterpret_cast<const float4*>(xp1 + (size_t)(t + 1) * 64);
        }

        FMA4(acc0, x0.x, a0)  FMA4(acc1, x1.x, a0)
        FMA4(acc0, x0.y, a1)  FMA4(acc1, x1.y, a1)
        FMA4(acc0, x0.z, a2)  FMA4(acc1, x1.z, a2)
        FMA4(acc0, x0.w, a3)  FMA4(acc1, x1.w, a3)
    }

    // reduce over the 16 kq groups (lane = 4*kq + rq)
    RED(4) RED(8) RED(16) RED(32)

    if (lane < 4) {   // kq == 0, lane == rq
        *reinterpret_cast<float4*>(&t_s[2 * wv + 0][lane * 4]) = acc0;
        *reinterpret_cast<float4*>(&t_s[2 * wv + 1][lane * 4]) = acc1;
    }
    __syncthreads();

    // ---------------- Phase B: O = T @ B (row pair per wave) ----------------
    const int m = 2 * wv;                       // rows m, m+1
    float* opa = O + (m0 + m) * (size_t)ND;
    float* opb = opa + ND;

    #pragma unroll 1
    for (int cc = 0; cc < ND / NCHUNK; ++cc) {
        // stage B[0..15][cc*512 .. +511] -> bs, fully coalesced
        #pragma unroll 2
        for (int i = 0; i < 8; ++i) {
            const int p   = i * BLK + tid;      // float4 slot 0..2047
            const int row = p >> 7;             // 128 float4 per B row-chunk
            const int c4  = p & 127;
            *reinterpret_cast<float4*>(&bs[p * 4]) =
                *reinterpret_cast<const float4*>(
                    Bm + (size_t)row * ND + cc * NCHUNK + c4 * 4);
        }
        __syncthreads();

        // broadcast t reads (cannot be hoisted across the barrier)
        const float4 ta0 = *reinterpret_cast<const float4*>(&t_s[m][0]);
        const float4 ta1 = *reinterpret_cast<const float4*>(&t_s[m][4]);
        const float4 ta2 = *reinterpret_cast<const float4*>(&t_s[m][8]);
        const float4 ta3 = *reinterpret_cast<const float4*>(&t_s[m][12]);
        const float4 tb0 = *reinterpret_cast<const float4*>(&t_s[m + 1][0]);
        const float4 tb1 = *reinterpret_cast<const float4*>(&t_s[m + 1][4]);
        const float4 tb2 = *reinterpret_cast<const float4*>(&t_s[m + 1][8]);
        const float4 tb3 = *reinterpret_cast<const float4*>(&t_s[m + 1][12]);

        #pragma unroll
        for (int j = 0; j < 2; ++j) {
            const int c4 = lane + 64 * j;       // col quad within chunk
            const float* bp = &bs[c4 * 4];
            float4 oa = {0.f, 0.f, 0.f, 0.f};
            float4 ob = {0.f, 0.f, 0.f, 0.f};
            FMAB2(ta0.x, tb0.x, 0)  FMAB2(ta0.y, tb0.y, 1)
            FMAB2(ta0.z, tb0.z, 2)  FMAB2(ta0.w, tb0.w, 3)
            FMAB2(ta1.x, tb1.x, 4)  FMAB2(ta1.y, tb1.y, 5)
            FMAB2(ta1.z, tb1.z, 6)  FMAB2(ta1.w, tb1.w, 7)
            FMAB2(ta2.x, tb2.x, 8)  FMAB2(ta2.y, tb2.y, 9)
            FMAB2(ta2.z, tb2.z, 10) FMAB2(ta2.w, tb2.w, 11)
            FMAB2(ta3.x, tb3.x, 12) FMAB2(ta3.y, tb3.y, 13)
            FMAB2(ta3.z, tb3.z, 14) FMAB2(ta3.w, tb3.w, 15)
            *reinterpret_cast<float4*>(opa + cc * NCHUNK + c4 * 4) = oa;
            *reinterpret_cast<float4*>(opb + cc * NCHUNK + c4 * 4) = ob;
        }
        __syncthreads();
    }
}

extern "C" void kernel_launch(void* const* d_in, const int* in_sizes, int n_in,
                              void* d_out, int out_size, void* d_ws, size_t ws_size,
                              hipStream_t stream) {
    const float* X  = (const float*)d_in[0];   // [4,2048,4096] fp32
    const float* A  = (const float*)d_in[1];   // [4096,16]     fp32
    const float* Bm = (const float*)d_in[2];   // [16,4096]     fp32
    float* O = (float*)d_out;                  // [4,2048,4096] fp32
    lora_fused<<<8192 / MB, BLK, 0, stream>>>(X, A, Bm, O);
}